// Round 3
// baseline (344.315 us; speedup 1.0000x reference)
//
#include <hip/hip_runtime.h>
#include <math.h>

// B=4, C=64, H=W=64 -> N=4096. fp32 in/out; fp16 MFMA internally.
// Precision: Q split hi/lo fp16 (exact), K/V/P single fp16. fp16 products are
// exact in fp32 accumulate -> S error comes only from K's 2^-11 rounding
// (logit sigma ~0.002). Validated error model: round-2 bf16 P,V gave 0.0156.
#define T_N 4096
#define T_C 64
#define T_B 4

typedef __attribute__((ext_vector_type(8))) _Float16 f16x8;  // 4 VGPRs
typedef __attribute__((ext_vector_type(4))) float f32x4;     // MFMA acc

__device__ inline unsigned short f2h(float f) {
    union { _Float16 h; unsigned short s; } u; u.h = (_Float16)f; return u.s;
}
__device__ inline float h2f(unsigned short s) {
    union { unsigned short s; _Float16 h; } u; u.s = s; return (float)u.h;
}

// ---------------------------------------------------------------------------
// Kernel 1: fused QKV projection -> fp16 outputs.
//   qt_hi/qt_lo, kt : (B, N, C)  (pixel-major, channels contiguous)
//   vb             : (B, C, N)  (channel-major, pixels contiguous)
// grid (N/32, B) = 512 blocks, 128 threads. Weights in LDS (48 KB, fp32).
// Lane map: oi=(tid&15)*4 channels, nj=(tid>>4)*4 pixels -> the (N,C) stores
// from 16 consecutive lanes cover one full 128 B pixel row (coalesced).
// ---------------------------------------------------------------------------
__global__ __launch_bounds__(128) void qkv_kernel(
    const float* __restrict__ x,
    const float* __restrict__ Wq, const float* __restrict__ bq,
    const float* __restrict__ Wk, const float* __restrict__ bk,
    const float* __restrict__ Wv, const float* __restrict__ bv,
    unsigned short* __restrict__ qt_hi, unsigned short* __restrict__ qt_lo,
    unsigned short* __restrict__ kt, unsigned short* __restrict__ vb)
{
    __shared__ __align__(16) float wqs[4096];
    __shared__ __align__(16) float wks[4096];
    __shared__ __align__(16) float wvs[4096];

    const int tid = threadIdx.x;
    const int n0  = blockIdx.x * 32;
    const int b   = blockIdx.y;
    const float* xb = x + (size_t)b * T_C * T_N;

    for (int i = tid; i < 1024; i += 128) {
        ((float4*)wqs)[i] = ((const float4*)Wq)[i];
        ((float4*)wks)[i] = ((const float4*)Wk)[i];
        ((float4*)wvs)[i] = ((const float4*)Wv)[i];
    }

    const int oi = (tid & 15) * 4;   // channel base
    const int nj = (tid >> 4) * 4;   // pixel base (0..28)

    float aq[4][4], ak[4][4], av[4][4];   // [u=channel][w=pixel]
    #pragma unroll
    for (int u = 0; u < 4; ++u) {
        const float bqv = bq[oi + u], bkv = bk[oi + u], bvv = bv[oi + u];
        #pragma unroll
        for (int w = 0; w < 4; ++w) { aq[u][w] = bqv; ak[u][w] = bkv; av[u][w] = bvv; }
    }
    __syncthreads();

    for (int c0 = 0; c0 < 64; c0 += 4) {
        float xa[4][4];
        #pragma unroll
        for (int cc = 0; cc < 4; ++cc) {
            const float4 xv = *(const float4*)&xb[(c0 + cc) * T_N + n0 + nj];
            xa[cc][0] = xv.x; xa[cc][1] = xv.y; xa[cc][2] = xv.z; xa[cc][3] = xv.w;
        }
        #pragma unroll
        for (int u = 0; u < 4; ++u) {
            const float4 q4 = *(const float4*)&wqs[(oi + u) * 64 + c0];
            const float4 k4 = *(const float4*)&wks[(oi + u) * 64 + c0];
            const float4 v4 = *(const float4*)&wvs[(oi + u) * 64 + c0];
            const float qa[4] = {q4.x, q4.y, q4.z, q4.w};
            const float ka[4] = {k4.x, k4.y, k4.z, k4.w};
            const float va[4] = {v4.x, v4.y, v4.z, v4.w};
            #pragma unroll
            for (int cc = 0; cc < 4; ++cc)
                #pragma unroll
                for (int w = 0; w < 4; ++w) {
                    aq[u][w] = fmaf(qa[cc], xa[cc][w], aq[u][w]);
                    ak[u][w] = fmaf(ka[cc], xa[cc][w], ak[u][w]);
                    av[u][w] = fmaf(va[cc], xa[cc][w], av[u][w]);
                }
        }
    }

    union U4 { ushort4 v; unsigned short s[4]; };

    // Q hi/lo + K stores, (B,N,C): lanes 0..15 cover one pixel row contiguously
    #pragma unroll
    for (int w = 0; w < 4; ++w) {
        U4 hq, lq, hk;
        #pragma unroll
        for (int u = 0; u < 4; ++u) {
            const float fq = aq[u][w];
            const unsigned short h = f2h(fq);
            hq.s[u] = h; lq.s[u] = f2h(fq - h2f(h));
            hk.s[u] = f2h(ak[u][w]);
        }
        const size_t off = ((size_t)b * T_N + n0 + nj + w) * 64 + oi;
        *(ushort4*)&qt_hi[off] = hq.v;
        *(ushort4*)&qt_lo[off] = lq.v;
        *(ushort4*)&kt[off]    = hk.v;
    }
    // V, (B,C,N)
    #pragma unroll
    for (int u = 0; u < 4; ++u) {
        U4 hv;
        #pragma unroll
        for (int w = 0; w < 4; ++w) hv.s[w] = f2h(av[u][w]);
        *(ushort4*)&vb[((size_t)(b * 64 + oi + u)) * T_N + n0 + nj] = hv.v;
    }
}

// ---------------------------------------------------------------------------
// Kernel 2: flash attention via MFMA 16x16x32 f16.
// grid (N/32, B) = 512 blocks (2 blocks/CU), 128 threads (2 waves).
// Wave wv owns query rows wv*16..wv*16+15 of the 32-query tile.
// S = (qh + ql) * k~  : 2 MFMAs per K-fragment, K fragment read once.
// Online softmax; P -> LDS (fp16) -> B-operand; O += V*P^T via MFMA.
// LDS rows padded to 72 shorts (144 B) -> uniform bank spread on b128 ops.
// ---------------------------------------------------------------------------
__global__ __launch_bounds__(128) void attn_kernel(
    const unsigned short* __restrict__ qt_hi, const unsigned short* __restrict__ qt_lo,
    const unsigned short* __restrict__ kt, const unsigned short* __restrict__ vb,
    float* __restrict__ out)
{
    __shared__ __align__(16) unsigned short qs_hi[32 * 72];
    __shared__ __align__(16) unsigned short qs_lo[32 * 72];
    __shared__ __align__(16) unsigned short ks[64 * 72];
    __shared__ __align__(16) unsigned short vs[64 * 72];
    __shared__ __align__(16) unsigned short ps[32 * 72];
    __shared__ float as_l[32], ls_l[32];

    const int tid  = threadIdx.x;
    const int n0   = blockIdx.x * 32;
    const int b    = blockIdx.y;
    const int wv   = tid >> 6;       // wave 0..1
    const int lane = tid & 63;
    const int quad = lane >> 4;      // 0..3
    const int col  = lane & 15;      // 0..15

    const size_t bN = (size_t)b * T_N;

    // stage Q tile hi/lo (32 rows x 64 ch)
    for (int i = tid; i < 512; i += 128) {
        if (i < 256) {
            const int row = i >> 3, cc = i & 7;
            *(float4*)&qs_hi[row * 72 + cc * 8] =
                *(const float4*)&qt_hi[(bN + n0 + row) * 64 + cc * 8];
        } else {
            const int j = i - 256, row = j >> 3, cc = j & 7;
            *(float4*)&qs_lo[row * 72 + cc * 8] =
                *(const float4*)&qt_lo[(bN + n0 + row) * 64 + cc * 8];
        }
    }
    __syncthreads();

    // persistent Q A-fragments: A[m=col][k = s*32 + quad*8 + j]
    f16x8 qh[2], ql[2];
    #pragma unroll
    for (int s = 0; s < 2; ++s) {
        qh[s] = *(const f16x8*)&qs_hi[(wv * 16 + col) * 72 + s * 32 + quad * 8];
        ql[s] = *(const f16x8*)&qs_lo[(wv * 16 + col) * 72 + s * 32 + quad * 8];
    }

    f32x4 O[4];
    #pragma unroll
    for (int t = 0; t < 4; ++t) O[t] = (f32x4){0.f, 0.f, 0.f, 0.f};
    float m_st[4], l_st[4];
    #pragma unroll
    for (int r = 0; r < 4; ++r) { m_st[r] = -INFINITY; l_st[r] = 0.f; }

    for (int ktile = 0; ktile < 64; ++ktile) {
        const int m0 = ktile * 64;
        __syncthreads();   // previous iteration's ks/vs reads done
        for (int i = tid; i < 1024; i += 128) {
            if (i < 512) {
                const int row = i >> 3, cc = i & 7;
                *(float4*)&ks[row * 72 + cc * 8] =
                    *(const float4*)&kt[(bN + m0 + row) * 64 + cc * 8];
            } else {
                const int j = i - 512, row = j >> 3, cc = j & 7;
                *(float4*)&vs[row * 72 + cc * 8] =
                    *(const float4*)&vb[((size_t)(b * 64 + row)) * T_N + m0 + cc * 8];
            }
        }
        __syncthreads();

        // --- S = Q^T K: 4 key sub-tiles; K fragment shared by hi+lo MFMAs ---
        f32x4 acc[4];
        #pragma unroll
        for (int t = 0; t < 4; ++t) acc[t] = (f32x4){0.f, 0.f, 0.f, 0.f};
        #pragma unroll
        for (int s = 0; s < 2; ++s) {
            #pragma unroll
            for (int t = 0; t < 4; ++t) {
                const f16x8 kf =
                    *(const f16x8*)&ks[(t * 16 + col) * 72 + s * 32 + quad * 8];
                acc[t] = __builtin_amdgcn_mfma_f32_16x16x32_f16(qh[s], kf, acc[t], 0, 0, 0);
                acc[t] = __builtin_amdgcn_mfma_f32_16x16x32_f16(ql[s], kf, acc[t], 0, 0, 0);
            }
        }

        // --- online softmax; lane holds S[q = wv*16+quad*4+r][key = 16t+col] ---
        float alpha[4];
        #pragma unroll
        for (int r = 0; r < 4; ++r) {
            float mx = fmaxf(fmaxf(acc[0][r], acc[1][r]), fmaxf(acc[2][r], acc[3][r]));
            #pragma unroll
            for (int off = 1; off < 16; off <<= 1)
                mx = fmaxf(mx, __shfl_xor(mx, off));
            const float mnew = fmaxf(m_st[r], mx);
            alpha[r] = __expf(m_st[r] - mnew);
            float p[4], sum = 0.f;
            #pragma unroll
            for (int t = 0; t < 4; ++t) {
                p[t] = __expf(acc[t][r] - mnew);
                sum += p[t];
            }
            #pragma unroll
            for (int off = 1; off < 16; off <<= 1)
                sum += __shfl_xor(sum, off);
            l_st[r] = alpha[r] * l_st[r] + sum;
            m_st[r] = mnew;
            #pragma unroll
            for (int t = 0; t < 4; ++t)
                ps[(wv * 16 + quad * 4 + r) * 72 + t * 16 + col] = f2h(p[t]);
        }
        if (col == 0) {
            #pragma unroll
            for (int r = 0; r < 4; ++r) as_l[wv * 16 + quad * 4 + r] = alpha[r];
        }

        // --- O = alpha*O + V P^T (ps/as_l wave-local; lgkmcnt ordering) ---
        const float al = as_l[wv * 16 + col];
        f16x8 pf[2];
        #pragma unroll
        for (int s2 = 0; s2 < 2; ++s2)
            pf[s2] = *(const f16x8*)&ps[(wv * 16 + col) * 72 + s2 * 32 + quad * 8];
        #pragma unroll
        for (int tc = 0; tc < 4; ++tc) {
            O[tc] *= al;
            #pragma unroll
            for (int s2 = 0; s2 < 2; ++s2) {
                const f16x8 vf =
                    *(const f16x8*)&vs[(tc * 16 + col) * 72 + s2 * 32 + quad * 8];
                O[tc] = __builtin_amdgcn_mfma_f32_16x16x32_f16(vf, pf[s2], O[tc], 0, 0, 0);
            }
        }
    }

    // --- epilogue: O element is c=tc*16+quad*4+r, q=wv*16+col ---
    if (col == 0) {
        #pragma unroll
        for (int r = 0; r < 4; ++r) ls_l[wv * 16 + quad * 4 + r] = l_st[r];
    }
    const float inv = 1.f / ls_l[wv * 16 + col];
    #pragma unroll
    for (int tc = 0; tc < 4; ++tc) {
        #pragma unroll
        for (int r = 0; r < 4; ++r) {
            out[((size_t)(b * 64 + tc * 16 + quad * 4 + r)) * T_N + n0 + wv * 16 + col] =
                O[tc][r] * inv;
        }
    }
}

// ---------------------------------------------------------------------------
extern "C" void kernel_launch(void* const* d_in, const int* in_sizes, int n_in,
                              void* d_out, int out_size, void* d_ws, size_t ws_size,
                              hipStream_t stream) {
    const float* x  = (const float*)d_in[0];
    const float* Wq = (const float*)d_in[1];
    const float* bq = (const float*)d_in[2];
    const float* Wk = (const float*)d_in[3];
    const float* bk = (const float*)d_in[4];
    const float* Wv = (const float*)d_in[5];
    const float* bv = (const float*)d_in[6];
    float* outp = (float*)d_out;

    // ws: 4 fp16 arrays of B*N*C = 1,048,576 elems (2 MB) each -> 8 MB
    const size_t elems = (size_t)T_B * T_N * T_C;
    unsigned short* qt_hi = (unsigned short*)d_ws;
    unsigned short* qt_lo = qt_hi + elems;
    unsigned short* ktp   = qt_lo + elems;
    unsigned short* vbuf  = ktp + elems;

    qkv_kernel<<<dim3(T_N / 32, T_B), 128, 0, stream>>>(
        x, Wq, bq, Wk, bk, Wv, bv, qt_hi, qt_lo, ktp, vbuf);
    attn_kernel<<<dim3(T_N / 32, T_B), 128, 0, stream>>>(
        qt_hi, qt_lo, ktp, vbuf, outp);
}

// Round 4
// 152.888 us; speedup vs baseline: 2.2521x; 2.2521x over previous
//
#include <hip/hip_runtime.h>
#include <math.h>

// B=4, C=64, H=W=64 -> N=4096. fp32 in/out; fp16 MFMA internally.
// Precision: Q split hi/lo fp16 (exact products in fp32 acc); K/V/P fp16.
// Split-K flash: 4 key-slices per (batch, 64-query tile); fp16 unnormalized
// partial O + fp32 (m,l) per slice; streaming combine pass.
#define T_N 4096
#define T_C 64
#define T_B 4
#define NSLICE 4
#define TILES_PER_SLICE (64 / NSLICE)   // 16 K-tiles of 64 keys each

typedef __attribute__((ext_vector_type(8))) _Float16 f16x8;  // 4 VGPRs
typedef __attribute__((ext_vector_type(4))) float f32x4;     // MFMA acc

__device__ inline unsigned short f2h(float f) {
    union { _Float16 h; unsigned short s; } u; u.h = (_Float16)f; return u.s;
}
__device__ inline float h2f(unsigned short s) {
    union { unsigned short s; _Float16 h; } u; u.s = s; return (float)u.h;
}

// ---------------------------------------------------------------------------
// Kernel 1: QKV projection, one projection per block (p = blockIdx.z).
//   p=0: Q -> qt_hi/qt_lo (B,N,C);  p=1: K -> kt (B,N,C);  p=2: V -> vb (B,C,N)
// grid (N/32, B, 3) = 1536 blocks, 128 threads (12 waves/CU when resident).
// W staged TRANSPOSED in LDS, pitch 68 floats -> b128 reads 2-way aliased only.
// ---------------------------------------------------------------------------
__global__ __launch_bounds__(128) void qkv_kernel(
    const float* __restrict__ x,
    const float* __restrict__ Wq, const float* __restrict__ bq,
    const float* __restrict__ Wk, const float* __restrict__ bk,
    const float* __restrict__ Wv, const float* __restrict__ bv,
    unsigned short* __restrict__ qt_hi, unsigned short* __restrict__ qt_lo,
    unsigned short* __restrict__ kt, unsigned short* __restrict__ vb)
{
    __shared__ __align__(16) float wst[64 * 68];   // wst[c][o] = W[o][c]

    const int tid = threadIdx.x;
    const int n0  = blockIdx.x * 32;
    const int b   = blockIdx.y;
    const int p   = blockIdx.z;
    const float* W    = (p == 0) ? Wq : (p == 1) ? Wk : Wv;
    const float* bias = (p == 0) ? bq : (p == 1) ? bk : bv;
    const float* xb   = x + (size_t)b * T_C * T_N;

    // stage W transposed: chunk i -> o = i>>4, c4 = (i&15)*4
    for (int i = tid; i < 1024; i += 128) {
        const int o = i >> 4, c4 = (i & 15) * 4;
        const float4 w4 = ((const float4*)W)[i];
        wst[(c4 + 0) * 68 + o] = w4.x;
        wst[(c4 + 1) * 68 + o] = w4.y;
        wst[(c4 + 2) * 68 + o] = w4.z;
        wst[(c4 + 3) * 68 + o] = w4.w;
    }

    // lane map chosen so this projection's OUTPUT stores coalesce
    const int oi = (p < 2) ? (tid & 15) * 4 : (tid >> 3) * 4;   // channel base
    const int nj = (p < 2) ? (tid >> 4) * 4 : (tid & 7) * 4;    // pixel base

    float acc[4][4];   // [u=channel][w=pixel]
    #pragma unroll
    for (int u = 0; u < 4; ++u) {
        const float bv_ = bias[oi + u];
        #pragma unroll
        for (int w = 0; w < 4; ++w) acc[u][w] = bv_;
    }
    __syncthreads();

    for (int c0 = 0; c0 < 64; c0 += 4) {
        float xa[4][4];
        #pragma unroll
        for (int cc = 0; cc < 4; ++cc) {
            const float4 xv = *(const float4*)&xb[(c0 + cc) * T_N + n0 + nj];
            xa[cc][0] = xv.x; xa[cc][1] = xv.y; xa[cc][2] = xv.z; xa[cc][3] = xv.w;
        }
        #pragma unroll
        for (int cc = 0; cc < 4; ++cc) {
            const float4 w4 = *(const float4*)&wst[(c0 + cc) * 68 + oi];
            const float wa[4] = {w4.x, w4.y, w4.z, w4.w};
            #pragma unroll
            for (int u = 0; u < 4; ++u)
                #pragma unroll
                for (int w = 0; w < 4; ++w)
                    acc[u][w] = fmaf(wa[u], xa[cc][w], acc[u][w]);
        }
    }

    union U4 { ushort4 v; unsigned short s[4]; };

    if (p == 0) {          // Q -> hi/lo, (B,N,C)
        #pragma unroll
        for (int w = 0; w < 4; ++w) {
            U4 hq, lq;
            #pragma unroll
            for (int u = 0; u < 4; ++u) {
                const float f = acc[u][w];
                const unsigned short h = f2h(f);
                hq.s[u] = h; lq.s[u] = f2h(f - h2f(h));
            }
            const size_t off = ((size_t)b * T_N + n0 + nj + w) * 64 + oi;
            *(ushort4*)&qt_hi[off] = hq.v;
            *(ushort4*)&qt_lo[off] = lq.v;
        }
    } else if (p == 1) {   // K, (B,N,C)
        #pragma unroll
        for (int w = 0; w < 4; ++w) {
            U4 hk;
            #pragma unroll
            for (int u = 0; u < 4; ++u) hk.s[u] = f2h(acc[u][w]);
            *(ushort4*)&kt[((size_t)b * T_N + n0 + nj + w) * 64 + oi] = hk.v;
        }
    } else {               // V, (B,C,N)
        #pragma unroll
        for (int u = 0; u < 4; ++u) {
            U4 hv;
            #pragma unroll
            for (int w = 0; w < 4; ++w) hv.s[w] = f2h(acc[u][w]);
            *(ushort4*)&vb[((size_t)(b * 64 + oi + u)) * T_N + n0 + nj] = hv.v;
        }
    }
}

// ---------------------------------------------------------------------------
// Kernel 2: flash-attention partial over one key-slice (16 tiles of 64 keys).
// grid (64, NSLICE, B) = 1024 blocks, 256 threads (4 waves); LDS ~28 KB ->
// 4 blocks/CU = 16 waves/CU. Q fragments loaded straight from global
// (coalesced; no Q LDS). Emits unnormalized O (fp16) + m,l (fp32).
// ---------------------------------------------------------------------------
__global__ __launch_bounds__(256, 4) void attn_kernel(
    const unsigned short* __restrict__ qt_hi, const unsigned short* __restrict__ qt_lo,
    const unsigned short* __restrict__ kt, const unsigned short* __restrict__ vb,
    unsigned short* __restrict__ o_part, float* __restrict__ mp, float* __restrict__ lp)
{
    __shared__ __align__(16) unsigned short ks[64 * 72];
    __shared__ __align__(16) unsigned short vs[64 * 72];
    __shared__ __align__(16) unsigned short ps[64 * 72];
    __shared__ float as_l[64];

    const int tid   = threadIdx.x;
    const int n0    = blockIdx.x * 64;
    const int slice = blockIdx.y;
    const int b     = blockIdx.z;
    const int wv    = tid >> 6;
    const int lane  = tid & 63;
    const int quad  = lane >> 4;
    const int col   = lane & 15;

    const size_t bN = (size_t)b * T_N;

    // Q A-fragments straight from global: A[m=col][k=s*32+quad*8+j]
    f16x8 qh[2], ql[2];
    #pragma unroll
    for (int s = 0; s < 2; ++s) {
        const size_t qoff = (bN + n0 + wv * 16 + col) * 64 + s * 32 + quad * 8;
        qh[s] = *(const f16x8*)&qt_hi[qoff];
        ql[s] = *(const f16x8*)&qt_lo[qoff];
    }

    f32x4 O[4];
    #pragma unroll
    for (int t = 0; t < 4; ++t) O[t] = (f32x4){0.f, 0.f, 0.f, 0.f};
    float m_st[4], l_st[4];
    #pragma unroll
    for (int r = 0; r < 4; ++r) { m_st[r] = -INFINITY; l_st[r] = 0.f; }

    for (int it = 0; it < TILES_PER_SLICE; ++it) {
        const int m0 = (slice * TILES_PER_SLICE + it) * 64;
        __syncthreads();   // previous iteration's ks/vs reads done
        for (int i = tid; i < 1024; i += 256) {
            if (i < 512) {
                const int row = i >> 3, cc = i & 7;
                *(float4*)&ks[row * 72 + cc * 8] =
                    *(const float4*)&kt[(bN + m0 + row) * 64 + cc * 8];
            } else {
                const int j = i - 512, row = j >> 3, cc = j & 7;
                *(float4*)&vs[row * 72 + cc * 8] =
                    *(const float4*)&vb[((size_t)(b * 64 + row)) * T_N + m0 + cc * 8];
            }
        }
        __syncthreads();

        // --- S = Q^T K: 4 key sub-tiles; K fragment shared by hi+lo MFMAs ---
        f32x4 acc[4];
        #pragma unroll
        for (int t = 0; t < 4; ++t) acc[t] = (f32x4){0.f, 0.f, 0.f, 0.f};
        #pragma unroll
        for (int s = 0; s < 2; ++s) {
            #pragma unroll
            for (int t = 0; t < 4; ++t) {
                const f16x8 kf =
                    *(const f16x8*)&ks[(t * 16 + col) * 72 + s * 32 + quad * 8];
                acc[t] = __builtin_amdgcn_mfma_f32_16x16x32_f16(qh[s], kf, acc[t], 0, 0, 0);
                acc[t] = __builtin_amdgcn_mfma_f32_16x16x32_f16(ql[s], kf, acc[t], 0, 0, 0);
            }
        }

        // --- online softmax; lane holds S[q=wv*16+quad*4+r][key=16t+col] ---
        float alpha[4];
        #pragma unroll
        for (int r = 0; r < 4; ++r) {
            float mx = fmaxf(fmaxf(acc[0][r], acc[1][r]), fmaxf(acc[2][r], acc[3][r]));
            #pragma unroll
            for (int off = 1; off < 16; off <<= 1)
                mx = fmaxf(mx, __shfl_xor(mx, off));
            const float mnew = fmaxf(m_st[r], mx);
            alpha[r] = __expf(m_st[r] - mnew);
            float p[4], sum = 0.f;
            #pragma unroll
            for (int t = 0; t < 4; ++t) {
                p[t] = __expf(acc[t][r] - mnew);
                sum += p[t];
            }
            #pragma unroll
            for (int off = 1; off < 16; off <<= 1)
                sum += __shfl_xor(sum, off);
            l_st[r] = alpha[r] * l_st[r] + sum;
            m_st[r] = mnew;
            #pragma unroll
            for (int t = 0; t < 4; ++t)
                ps[(wv * 16 + quad * 4 + r) * 72 + t * 16 + col] = f2h(p[t]);
        }
        if (col == 0) {
            #pragma unroll
            for (int r = 0; r < 4; ++r) as_l[wv * 16 + quad * 4 + r] = alpha[r];
        }

        // --- O = alpha*O + V P^T (ps/as_l wave-local; lgkmcnt ordering) ---
        const float al = as_l[wv * 16 + col];
        f16x8 pf[2];
        #pragma unroll
        for (int s2 = 0; s2 < 2; ++s2)
            pf[s2] = *(const f16x8*)&ps[(wv * 16 + col) * 72 + s2 * 32 + quad * 8];
        #pragma unroll
        for (int tc = 0; tc < 4; ++tc) {
            O[tc] *= al;
            #pragma unroll
            for (int s2 = 0; s2 < 2; ++s2) {
                const f16x8 vf =
                    *(const f16x8*)&vs[(tc * 16 + col) * 72 + s2 * 32 + quad * 8];
                O[tc] = __builtin_amdgcn_mfma_f32_16x16x32_f16(vf, pf[s2], O[tc], 0, 0, 0);
            }
        }
    }

    // --- epilogue: unnormalized partial O (fp16) + m,l (fp32) ---
    // O element: c = tc*16+quad*4+r, q = wv*16+col
    #pragma unroll
    for (int tc = 0; tc < 4; ++tc) {
        #pragma unroll
        for (int r = 0; r < 4; ++r) {
            const int c = tc * 16 + quad * 4 + r;
            o_part[((size_t)((slice * T_B + b) * 64 + c)) * T_N + n0 + wv * 16 + col] =
                f2h(O[tc][r]);
        }
    }
    if (col == 0) {
        #pragma unroll
        for (int r = 0; r < 4; ++r) {
            const size_t off = (size_t)(slice * T_B + b) * T_N + n0 + wv * 16 + quad * 4 + r;
            mp[off] = m_st[r];
            lp[off] = l_st[r];
        }
    }
}

// ---------------------------------------------------------------------------
// Kernel 3: combine slices. out[b,c,n] = sum_s O_s[c,n]*w_s(n) / sum_s l_s*w_s(n)
// grid (N/32, B) = 512 blocks, 256 threads. Pure streaming (~16 MB).
// ---------------------------------------------------------------------------
__global__ __launch_bounds__(256) void combine_kernel(
    const unsigned short* __restrict__ o_part,
    const float* __restrict__ mp, const float* __restrict__ lp,
    float* __restrict__ out)
{
    __shared__ float wn[NSLICE][32];

    const int tid = threadIdx.x;
    const int n0  = blockIdx.x * 32;
    const int b   = blockIdx.y;

    if (tid < 32) {
        float m_s[NSLICE], l_s[NSLICE];
        #pragma unroll
        for (int s = 0; s < NSLICE; ++s) {
            const size_t off = (size_t)(s * T_B + b) * T_N + n0 + tid;
            m_s[s] = mp[off];
            l_s[s] = lp[off];
        }
        float M = m_s[0];
        #pragma unroll
        for (int s = 1; s < NSLICE; ++s) M = fmaxf(M, m_s[s]);
        float w_s[NSLICE], L = 0.f;
        #pragma unroll
        for (int s = 0; s < NSLICE; ++s) {
            w_s[s] = __expf(m_s[s] - M);
            L += l_s[s] * w_s[s];
        }
        const float inv = 1.f / L;
        #pragma unroll
        for (int s = 0; s < NSLICE; ++s) wn[s][tid] = w_s[s] * inv;
    }
    __syncthreads();

    for (int t = tid; t < 512; t += 256) {
        const int c = t >> 3, g = t & 7;
        float4 acc = make_float4(0.f, 0.f, 0.f, 0.f);
        #pragma unroll
        for (int s = 0; s < NSLICE; ++s) {
            const ushort4 o4 = *(const ushort4*)
                &o_part[((size_t)((s * T_B + b) * 64 + c)) * T_N + n0 + g * 4];
            acc.x = fmaf(h2f(o4.x), wn[s][g * 4 + 0], acc.x);
            acc.y = fmaf(h2f(o4.y), wn[s][g * 4 + 1], acc.y);
            acc.z = fmaf(h2f(o4.z), wn[s][g * 4 + 2], acc.z);
            acc.w = fmaf(h2f(o4.w), wn[s][g * 4 + 3], acc.w);
        }
        *(float4*)&out[((size_t)(b * 64 + c)) * T_N + n0 + g * 4] = acc;
    }
}

// ---------------------------------------------------------------------------
extern "C" void kernel_launch(void* const* d_in, const int* in_sizes, int n_in,
                              void* d_out, int out_size, void* d_ws, size_t ws_size,
                              hipStream_t stream) {
    const float* x  = (const float*)d_in[0];
    const float* Wq = (const float*)d_in[1];
    const float* bq = (const float*)d_in[2];
    const float* Wk = (const float*)d_in[3];
    const float* bk = (const float*)d_in[4];
    const float* Wv = (const float*)d_in[5];
    const float* bv = (const float*)d_in[6];
    float* outp = (float*)d_out;

    // ws: qt_hi/qt_lo/kt/vb fp16 (4 x 2 MB) + o_part fp16 (8 MB)
    //     + mp/lp fp32 (2 x 256 KB)  -> ~16.5 MB
    const size_t elems = (size_t)T_B * T_N * T_C;
    unsigned short* qt_hi  = (unsigned short*)d_ws;
    unsigned short* qt_lo  = qt_hi + elems;
    unsigned short* ktp    = qt_lo + elems;
    unsigned short* vbuf   = ktp + elems;
    unsigned short* o_part = vbuf + elems;                       // NSLICE*elems
    float* mp = (float*)(o_part + (size_t)NSLICE * elems);
    float* lp = mp + (size_t)NSLICE * T_B * T_N;

    qkv_kernel<<<dim3(T_N / 32, T_B, 3), 128, 0, stream>>>(
        x, Wq, bq, Wk, bk, Wv, bv, qt_hi, qt_lo, ktp, vbuf);
    attn_kernel<<<dim3(T_N / 64, NSLICE, T_B), 256, 0, stream>>>(
        qt_hi, qt_lo, ktp, vbuf, o_part, mp, lp);
    combine_kernel<<<dim3(T_N / 32, T_B), 256, 0, stream>>>(
        o_part, mp, lp, outp);
}

// Round 5
// 130.191 us; speedup vs baseline: 2.6447x; 1.1743x over previous
//
#include <hip/hip_runtime.h>
#include <math.h>

// B=4, C=64, H=W=64 -> N=4096. fp32 in/out; fp16 MFMA internally.
// qkv: MFMA GEMM, x split hi/lo fp16 (error = W fp16 rounding only).
// attn: split-K flash. S^T = K*Q^T so softmax rows sit in lanes (q=col) and
// P^T lands in registers in exactly the B-operand layout of 16x16x16 f16 MFMA.
#define T_N 4096
#define T_C 64
#define T_B 4
#define NSLICE 4
#define TILES_PER_SLICE (64 / NSLICE)

typedef __attribute__((ext_vector_type(8))) _Float16 f16x8;  // 4 VGPRs
typedef __attribute__((ext_vector_type(4))) _Float16 f16x4;  // 2 VGPRs
typedef __attribute__((ext_vector_type(4))) float f32x4;     // MFMA acc

__device__ inline unsigned short f2h(float f) {
    union { _Float16 h; unsigned short s; } u; u.h = (_Float16)f; return u.s;
}
__device__ inline float h2f(unsigned short s) {
    union { unsigned short s; _Float16 h; } u; u.s = s; return (float)u.h;
}

// ---------------------------------------------------------------------------
// Kernel 1: QKV projection via MFMA. One projection per block (p=blockIdx.z).
// grid (N/64, B, 3) = 768 blocks, 256 thr (4 waves; wave = one 16-pixel subtile).
// D[n][o] = sum_c X[c][n] W[o][c] (+bias): A = x^T (hi/lo fp16, staged
// transposed in LDS), B = W (fp16, row-major in LDS). Outputs:
//   p=0: qt_hi/qt_lo (B,N,C);  p=1: kt (B,N,C);  p=2: vb (B,C,N)
// ---------------------------------------------------------------------------
__global__ __launch_bounds__(256) void qkv_kernel(
    const float* __restrict__ x,
    const float* __restrict__ Wq, const float* __restrict__ bq,
    const float* __restrict__ Wk, const float* __restrict__ bk,
    const float* __restrict__ Wv, const float* __restrict__ bv,
    unsigned short* __restrict__ qt_hi, unsigned short* __restrict__ qt_lo,
    unsigned short* __restrict__ kt, unsigned short* __restrict__ vb)
{
    __shared__ __align__(16) unsigned short xsh[64 * 72];  // x^T hi: [pixel][ch]
    __shared__ __align__(16) unsigned short xsl[64 * 72];  // x^T lo
    __shared__ __align__(16) unsigned short wf[64 * 72];   // W fp16: [o][ch]

    const int tid = threadIdx.x;
    const int n0  = blockIdx.x * 64;
    const int b   = blockIdx.y;
    const int p   = blockIdx.z;
    const float* W    = (p == 0) ? Wq : (p == 1) ? Wk : Wv;
    const float* bias = (p == 0) ? bq : (p == 1) ? bk : bv;
    const float* xb   = x + (size_t)b * T_C * T_N;

    // stage W -> fp16 LDS [o][c], 8B contiguous writes
    for (int i = tid; i < 1024; i += 256) {
        const int o = i >> 4, c4 = (i & 15) * 4;
        const float4 w4 = ((const float4*)W)[i];
        f16x4 wh;
        wh[0] = (_Float16)w4.x; wh[1] = (_Float16)w4.y;
        wh[2] = (_Float16)w4.z; wh[3] = (_Float16)w4.w;
        *(f16x4*)&wf[o * 72 + c4] = wh;
    }
    // stage x -> hi/lo fp16, transposed [pixel][ch] (scalar b16 writes)
    for (int i = tid; i < 1024; i += 256) {
        const int c = i >> 4, nj4 = (i & 15) * 4;
        const float4 xv = *(const float4*)&xb[c * T_N + n0 + nj4];
        const float xa[4] = {xv.x, xv.y, xv.z, xv.w};
        #pragma unroll
        for (int j = 0; j < 4; ++j) {
            const unsigned short h = f2h(xa[j]);
            xsh[(nj4 + j) * 72 + c] = h;
            xsl[(nj4 + j) * 72 + c] = f2h(xa[j] - h2f(h));
        }
    }
    __syncthreads();

    const int wv_  = tid >> 6;      // wave = pixel subtile
    const int lane = tid & 63;
    const int quad = lane >> 4;
    const int col  = lane & 15;
    const size_t bN = (size_t)b * T_N;

    // A-frags: A[m=pixel][k=ch]: m=col -> pixel = wv_*16+col
    f16x8 xh[2], xl[2];
    #pragma unroll
    for (int s = 0; s < 2; ++s) {
        xh[s] = *(const f16x8*)&xsh[(wv_ * 16 + col) * 72 + s * 32 + quad * 8];
        xl[s] = *(const f16x8*)&xsl[(wv_ * 16 + col) * 72 + s * 32 + quad * 8];
    }

    #pragma unroll
    for (int osub = 0; osub < 4; ++osub) {
        f32x4 acc = (f32x4){0.f, 0.f, 0.f, 0.f};
        #pragma unroll
        for (int s = 0; s < 2; ++s) {
            // B[k=ch][n=o]: n=col -> o = osub*16+col
            const f16x8 wfr = *(const f16x8*)&wf[(osub * 16 + col) * 72 + s * 32 + quad * 8];
            acc = __builtin_amdgcn_mfma_f32_16x16x32_f16(xh[s], wfr, acc, 0, 0, 0);
            acc = __builtin_amdgcn_mfma_f32_16x16x32_f16(xl[s], wfr, acc, 0, 0, 0);
        }
        // acc[r]: pixel = wv_*16+quad*4+r, o = osub*16+col
        const float bb = bias[osub * 16 + col];
        if (p == 0) {
            #pragma unroll
            for (int r = 0; r < 4; ++r) {
                const float f = acc[r] + bb;
                const unsigned short h = f2h(f);
                const size_t off = (bN + n0 + wv_ * 16 + quad * 4 + r) * 64 + osub * 16 + col;
                qt_hi[off] = h;
                qt_lo[off] = f2h(f - h2f(h));
            }
        } else if (p == 1) {
            #pragma unroll
            for (int r = 0; r < 4; ++r)
                kt[(bN + n0 + wv_ * 16 + quad * 4 + r) * 64 + osub * 16 + col] =
                    f2h(acc[r] + bb);
        } else {
            union { ushort4 v; unsigned short s[4]; } hv;
            #pragma unroll
            for (int r = 0; r < 4; ++r) hv.s[r] = f2h(acc[r] + bb);
            *(ushort4*)&vb[((size_t)(b * 64 + osub * 16 + col)) * T_N +
                           n0 + wv_ * 16 + quad * 4] = hv.v;
        }
    }
}

// ---------------------------------------------------------------------------
// Kernel 2: flash-attention partial over one key-slice.
// grid (64, NSLICE, B) = 1024 blocks, 256 thr (4 waves), LDS 18.4 KB ->
// 4 blocks/CU (16 waves/CU). S^T = K*Q^T: A=K-frag, B=Q-frag (hi/lo).
// acc_t holds S^T[key=16t+quad*4+r][q=col]: softmax state is per-lane scalar
// (2 cross-quad shuffles); P^T stays in registers as the B-operand of
// mfma_f32_16x16x16f16 for O[c][q] += V*P^T. No P/alpha LDS traffic.
// ---------------------------------------------------------------------------
__global__ __launch_bounds__(256, 4) void attn_kernel(
    const unsigned short* __restrict__ qt_hi, const unsigned short* __restrict__ qt_lo,
    const unsigned short* __restrict__ kt, const unsigned short* __restrict__ vb,
    unsigned short* __restrict__ o_part, float* __restrict__ mp, float* __restrict__ lp)
{
    __shared__ __align__(16) unsigned short ks[64 * 72];   // [key][ch]
    __shared__ __align__(16) unsigned short vs[64 * 72];   // [ch][key]

    const int tid   = threadIdx.x;
    const int n0    = blockIdx.x * 64;
    const int slice = blockIdx.y;
    const int b     = blockIdx.z;
    const int wv_   = tid >> 6;
    const int lane  = tid & 63;
    const int quad  = lane >> 4;
    const int col   = lane & 15;

    const size_t bN = (size_t)b * T_N;
    const int q_own = n0 + wv_ * 16 + col;   // this lane's query

    // Q B-frags from global: B[k=ch][n=q]: n=col -> q_own, k=s*32+quad*8+j
    f16x8 qh[2], ql[2];
    #pragma unroll
    for (int s = 0; s < 2; ++s) {
        const size_t qoff = (bN + q_own) * 64 + s * 32 + quad * 8;
        qh[s] = *(const f16x8*)&qt_hi[qoff];
        ql[s] = *(const f16x8*)&qt_lo[qoff];
    }

    f32x4 O[4];
    #pragma unroll
    for (int t = 0; t < 4; ++t) O[t] = (f32x4){0.f, 0.f, 0.f, 0.f};
    float m_st = -INFINITY, l_st = 0.f;

    for (int it = 0; it < TILES_PER_SLICE; ++it) {
        const int m0 = (slice * TILES_PER_SLICE + it) * 64;
        __syncthreads();   // previous iteration's ks/vs reads done
        for (int i = tid; i < 1024; i += 256) {
            if (i < 512) {
                const int row = i >> 3, cc = i & 7;
                *(float4*)&ks[row * 72 + cc * 8] =
                    *(const float4*)&kt[(bN + m0 + row) * 64 + cc * 8];
            } else {
                const int j = i - 512, row = j >> 3, cc = j & 7;
                *(float4*)&vs[row * 72 + cc * 8] =
                    *(const float4*)&vb[((size_t)(b * 64 + row)) * T_N + m0 + cc * 8];
            }
        }
        __syncthreads();

        // --- S^T = K Q^T: acc[t] = S^T[key=16t+quad*4+r][q=col] ---
        f32x4 acc[4];
        #pragma unroll
        for (int t = 0; t < 4; ++t) acc[t] = (f32x4){0.f, 0.f, 0.f, 0.f};
        #pragma unroll
        for (int s = 0; s < 2; ++s) {
            #pragma unroll
            for (int t = 0; t < 4; ++t) {
                const f16x8 kf =   // A[m=key][k=ch]: m=col -> key = 16t+col
                    *(const f16x8*)&ks[(t * 16 + col) * 72 + s * 32 + quad * 8];
                acc[t] = __builtin_amdgcn_mfma_f32_16x16x32_f16(kf, qh[s], acc[t], 0, 0, 0);
                acc[t] = __builtin_amdgcn_mfma_f32_16x16x32_f16(kf, ql[s], acc[t], 0, 0, 0);
            }
        }

        // --- online softmax: row = q = col; reduce across quads only ---
        float mx = -INFINITY;
        #pragma unroll
        for (int t = 0; t < 4; ++t)
            #pragma unroll
            for (int r = 0; r < 4; ++r) mx = fmaxf(mx, acc[t][r]);
        mx = fmaxf(mx, __shfl_xor(mx, 16));
        mx = fmaxf(mx, __shfl_xor(mx, 32));
        const float mnew = fmaxf(m_st, mx);
        const float alpha = __expf(m_st - mnew);
        float sum = 0.f;
        f16x4 pf[4];
        #pragma unroll
        for (int t = 0; t < 4; ++t) {
            #pragma unroll
            for (int r = 0; r < 4; ++r) {
                const float pv = __expf(acc[t][r] - mnew);
                sum += pv;
                pf[t][r] = (_Float16)pv;   // B[k=key=16t+quad*4+r][n=q=col]
            }
        }
        sum += __shfl_xor(sum, 16);
        sum += __shfl_xor(sum, 32);
        l_st = alpha * l_st + sum;
        m_st = mnew;

        // --- O = alpha*O + V P^T via 16x16x16 MFMA (P in registers) ---
        #pragma unroll
        for (int tc = 0; tc < 4; ++tc) {
            O[tc] *= alpha;
            #pragma unroll
            for (int t = 0; t < 4; ++t) {
                const f16x4 vf =   // A[m=c][k=key]: m=col -> c = tc*16+col
                    *(const f16x4*)&vs[(tc * 16 + col) * 72 + t * 16 + quad * 4];
                O[tc] = __builtin_amdgcn_mfma_f32_16x16x16f16(vf, pf[t], O[tc], 0, 0, 0);
            }
        }
    }

    // --- epilogue: O[tc][r]: c = tc*16+quad*4+r, q = col ---
    #pragma unroll
    for (int tc = 0; tc < 4; ++tc) {
        #pragma unroll
        for (int r = 0; r < 4; ++r) {
            o_part[((size_t)((slice * T_B + b) * 64 + tc * 16 + quad * 4 + r)) * T_N +
                   q_own] = f2h(O[tc][r]);
        }
    }
    if (quad == 0) {
        const size_t off = (size_t)(slice * T_B + b) * T_N + q_own;
        mp[off] = m_st;
        lp[off] = l_st;
    }
}

// ---------------------------------------------------------------------------
// Kernel 3: combine slices. grid (N/32, B), 256 thr. Pure streaming.
// ---------------------------------------------------------------------------
__global__ __launch_bounds__(256) void combine_kernel(
    const unsigned short* __restrict__ o_part,
    const float* __restrict__ mp, const float* __restrict__ lp,
    float* __restrict__ out)
{
    __shared__ float wn[NSLICE][32];

    const int tid = threadIdx.x;
    const int n0  = blockIdx.x * 32;
    const int b   = blockIdx.y;

    if (tid < 32) {
        float m_s[NSLICE], l_s[NSLICE];
        #pragma unroll
        for (int s = 0; s < NSLICE; ++s) {
            const size_t off = (size_t)(s * T_B + b) * T_N + n0 + tid;
            m_s[s] = mp[off];
            l_s[s] = lp[off];
        }
        float M = m_s[0];
        #pragma unroll
        for (int s = 1; s < NSLICE; ++s) M = fmaxf(M, m_s[s]);
        float w_s[NSLICE], L = 0.f;
        #pragma unroll
        for (int s = 0; s < NSLICE; ++s) {
            w_s[s] = __expf(m_s[s] - M);
            L += l_s[s] * w_s[s];
        }
        const float inv = 1.f / L;
        #pragma unroll
        for (int s = 0; s < NSLICE; ++s) wn[s][tid] = w_s[s] * inv;
    }
    __syncthreads();

    for (int t = tid; t < 512; t += 256) {
        const int c = t >> 3, g = t & 7;
        float4 acc = make_float4(0.f, 0.f, 0.f, 0.f);
        #pragma unroll
        for (int s = 0; s < NSLICE; ++s) {
            const ushort4 o4 = *(const ushort4*)
                &o_part[((size_t)((s * T_B + b) * 64 + c)) * T_N + n0 + g * 4];
            acc.x = fmaf(h2f(o4.x), wn[s][g * 4 + 0], acc.x);
            acc.y = fmaf(h2f(o4.y), wn[s][g * 4 + 1], acc.y);
            acc.z = fmaf(h2f(o4.z), wn[s][g * 4 + 2], acc.z);
            acc.w = fmaf(h2f(o4.w), wn[s][g * 4 + 3], acc.w);
        }
        *(float4*)&out[((size_t)(b * 64 + c)) * T_N + n0 + g * 4] = acc;
    }
}

// ---------------------------------------------------------------------------
extern "C" void kernel_launch(void* const* d_in, const int* in_sizes, int n_in,
                              void* d_out, int out_size, void* d_ws, size_t ws_size,
                              hipStream_t stream) {
    const float* x  = (const float*)d_in[0];
    const float* Wq = (const float*)d_in[1];
    const float* bq = (const float*)d_in[2];
    const float* Wk = (const float*)d_in[3];
    const float* bk = (const float*)d_in[4];
    const float* Wv = (const float*)d_in[5];
    const float* bv = (const float*)d_in[6];
    float* outp = (float*)d_out;

    const size_t elems = (size_t)T_B * T_N * T_C;
    unsigned short* qt_hi  = (unsigned short*)d_ws;
    unsigned short* qt_lo  = qt_hi + elems;
    unsigned short* ktp    = qt_lo + elems;
    unsigned short* vbuf   = ktp + elems;
    unsigned short* o_part = vbuf + elems;                       // NSLICE*elems
    float* mp = (float*)(o_part + (size_t)NSLICE * elems);
    float* lp = mp + (size_t)NSLICE * T_B * T_N;

    qkv_kernel<<<dim3(T_N / 64, T_B, 3), 256, 0, stream>>>(
        x, Wq, bq, Wk, bk, Wv, bv, qt_hi, qt_lo, ktp, vbuf);
    attn_kernel<<<dim3(T_N / 64, NSLICE, T_B), 256, 0, stream>>>(
        qt_hi, qt_lo, ktp, vbuf, o_part, mp, lp);
    combine_kernel<<<dim3(T_N / 32, T_B), 256, 0, stream>>>(
        o_part, mp, lp, outp);
}